// Round 1
// baseline (404.948 us; speedup 1.0000x reference)
//
#include <hip/hip_runtime.h>
#include <hip/hip_bf16.h>

// EnergyAttention: out = -sum(logsumexp(SCALE * (Q K^T), axis=-1)) / SCALE
// Q = hs @ qp^T + qb, K = hs @ kp^T + kb   per head (16 heads, qk_dim=64)
// hs: (2,2048,1024) f32; qp/kp: (16,64,1024) f32; biases (64,) f32.
// Scalar f32 output.

typedef __bf16 bf16_t;
typedef bf16_t bf16x8 __attribute__((ext_vector_type(8)));
typedef float f32x4 __attribute__((ext_vector_type(4)));

#define MFMA16(a, b, c) __builtin_amdgcn_mfma_f32_16x16x32_bf16(a, b, c, 0, 0, 0)

static constexpr int SEQ   = 2048;
static constexpr int BATCH = 2;
static constexpr int EMBED = 1024;
static constexpr int NH    = 16;
static constexpr int QKD   = 64;
static constexpr int M_TOT = BATCH * SEQ;      // 4096 rows (b*seq)
static constexpr int N_TOT = 2 * NH * QKD;     // 2048 cols: [0,1024)=Q, [1024,2048)=K

__device__ inline bf16x8 load_cvt8(const float* __restrict__ p) {
    f32x4 a = *(const f32x4*)p;
    f32x4 b = *(const f32x4*)(p + 4);
    bf16x8 r;
    r[0] = (bf16_t)a[0]; r[1] = (bf16_t)a[1]; r[2] = (bf16_t)a[2]; r[3] = (bf16_t)a[3];
    r[4] = (bf16_t)b[0]; r[5] = (bf16_t)b[1]; r[6] = (bf16_t)b[2]; r[7] = (bf16_t)b[3];
    return r;
}

// Phase 1: C[m][n] = sum_d A[m][d] * B[n][d]  (+bias), stored bf16.
// A = hidden_states (4096x1024), B = concat(query_proj, key_proj) (2048x1024).
// Block = 256 thr (4 waves); tile 64(M) x 64(N); wave w owns rows m0+16w..+15.
__global__ __launch_bounds__(256) void proj_kernel(
    const float* __restrict__ hs, const float* __restrict__ qp,
    const float* __restrict__ kp, const float* __restrict__ qb,
    const float* __restrict__ kb, bf16_t* __restrict__ qk)
{
    const int lane = threadIdx.x & 63;
    const int wave = threadIdx.x >> 6;
    const int m0   = blockIdx.y * 64 + wave * 16;
    const int n0   = blockIdx.x * 64;
    const int l15  = lane & 15;
    const int lk   = (lane >> 4) * 8;   // k-offset within 32-chunk (A/B frag layout)

    const float* arow = hs + (size_t)(m0 + l15) * EMBED + lk;

    const float* brow[4];
    float bias[4];
#pragma unroll
    for (int t = 0; t < 4; ++t) {
        int col = n0 + t * 16 + l15;
        int q   = col & 63;
        if (col < NH * QKD) { brow[t] = qp + (size_t)col * EMBED + lk;              bias[t] = qb[q]; }
        else                { brow[t] = kp + (size_t)(col - NH * QKD) * EMBED + lk; bias[t] = kb[q]; }
    }

    f32x4 acc[4] = {};
    for (int kk = 0; kk < EMBED; kk += 32) {
        bf16x8 af = load_cvt8(arow + kk);
#pragma unroll
        for (int t = 0; t < 4; ++t) {
            bf16x8 bfr = load_cvt8(brow[t] + kk);
            acc[t] = MFMA16(af, bfr, acc[t]);
        }
    }

    // C/D layout: col = lane&15, row = (lane>>4)*4 + j   [m89-verified]
#pragma unroll
    for (int t = 0; t < 4; ++t) {
        int col = n0 + t * 16 + l15;
#pragma unroll
        for (int j = 0; j < 4; ++j) {
            int row = m0 + (lane >> 4) * 4 + j;
            qk[(size_t)row * N_TOT + col] = (bf16_t)(acc[t][j] + bias[t]);
        }
    }
}

// Phase 2: per (b,h), S = Q_h K_h^T (2048x2048), row-wise sum of exp(SCALE*S),
// partial = sum over rows of log2(sumexp). Block = 4 waves x 16 rows = 64 rows.
__global__ __launch_bounds__(256) void lse_kernel(
    const bf16_t* __restrict__ qk, float* __restrict__ partials)
{
    const int lane = threadIdx.x & 63;
    const int wave = threadIdx.x >> 6;
    const int pair = blockIdx.y;            // b*16 + h
    const int b = pair >> 4, h = pair & 15;
    const int r0  = blockIdx.x * 64 + wave * 16;
    const int l15 = lane & 15;
    const int lk  = (lane >> 4) * 8;

    // Q fragments for this wave's 16 rows (k-dim = 64 -> two K=32 chunks), hoisted.
    const bf16_t* qbase = qk + (size_t)(b * SEQ + r0 + l15) * N_TOT + h * QKD + lk;
    bf16x8 q0 = *(const bf16x8*)(qbase);
    bf16x8 q1 = *(const bf16x8*)(qbase + 32);

    const bf16_t* kbase = qk + (size_t)(b * SEQ) * N_TOT + NH * QKD + h * QKD + lk;

    const float C1 = 0.125f * 1.44269504088896340736f;  // SCALE * log2(e)
    f32x4 sume = {};
    for (int ct = 0; ct < SEQ / 16; ++ct) {
        const bf16_t* kr = kbase + (size_t)(ct * 16 + l15) * N_TOT;
        bf16x8 k0 = *(const bf16x8*)kr;
        bf16x8 k1 = *(const bf16x8*)(kr + 32);
        f32x4 s = {};
        s = MFMA16(q0, k0, s);
        s = MFMA16(q1, k1, s);
#pragma unroll
        for (int j = 0; j < 4; ++j)
            sume[j] += exp2f(s[j] * C1);
    }

    // Sum over the 16 columns held across lanes (lane&15); rows live on (lane>>4)*4+j.
#pragma unroll
    for (int m = 1; m < 16; m <<= 1) {
#pragma unroll
        for (int j = 0; j < 4; ++j)
            sume[j] += __shfl_xor((float)sume[j], m);
    }

    float t = 0.f;
#pragma unroll
    for (int j = 0; j < 4; ++j)
        t += log2f(sume[j]);
    // t identical within each 16-lane group; sum the 4 groups -> wave's 16 rows.
    t += __shfl_xor(t, 16);
    t += __shfl_xor(t, 32);

    __shared__ float wsum[4];
    if (lane == 0) wsum[wave] = t;
    __syncthreads();
    if (threadIdx.x == 0)
        partials[blockIdx.y * gridDim.x + blockIdx.x] = wsum[0] + wsum[1] + wsum[2] + wsum[3];
}

__global__ __launch_bounds__(256) void final_kernel(
    const float* __restrict__ partials, int n, float* __restrict__ out)
{
    float s = 0.f;
    for (int i = threadIdx.x; i < n; i += 256) s += partials[i];
#pragma unroll
    for (int m = 1; m < 64; m <<= 1) s += __shfl_xor(s, m);
    __shared__ float ws[4];
    const int wave = threadIdx.x >> 6, lane = threadIdx.x & 63;
    if (lane == 0) ws[wave] = s;
    __syncthreads();
    if (threadIdx.x == 0) {
        float tot = ws[0] + ws[1] + ws[2] + ws[3];
        // out = -(1/SCALE) * sum(ln(sumexp)) = -8 * ln2 * sum(log2(sumexp))
        out[0] = -8.0f * 0.69314718055994530942f * tot;
    }
}

extern "C" void kernel_launch(void* const* d_in, const int* in_sizes, int n_in,
                              void* d_out, int out_size, void* d_ws, size_t ws_size,
                              hipStream_t stream)
{
    const float* hs = (const float*)d_in[0];
    const float* qp = (const float*)d_in[1];
    const float* kp = (const float*)d_in[2];
    const float* qb = (const float*)d_in[3];
    const float* kb = (const float*)d_in[4];

    // Workspace: QK bf16 matrix (16.8 MB) + 1024 partial sums.
    bf16_t* qk       = (bf16_t*)d_ws;
    float*  partials = (float*)((char*)d_ws + (size_t)M_TOT * N_TOT * sizeof(bf16_t));
    float*  out      = (float*)d_out;

    proj_kernel<<<dim3(N_TOT / 64, M_TOT / 64), 256, 0, stream>>>(hs, qp, kp, qb, kb, qk);
    lse_kernel<<<dim3(SEQ / 64, BATCH * NH), 256, 0, stream>>>(qk, partials);
    final_kernel<<<1, 256, 0, stream>>>(partials, (BATCH * NH) * (SEQ / 64), out);
}

// Round 2
// 71.437 us; speedup vs baseline: 5.6686x; 5.6686x over previous
//
#include <hip/hip_runtime.h>
#include <hip/hip_bf16.h>
#include <stdint.h>

// EnergyAttention: out = -sum(logsumexp(SCALE * (Q K^T), axis=-1)) / SCALE
// Q = hs @ qp^T + qb (pre-scaled by SCALE*log2e), K = hs @ kp^T + kb, bf16.

typedef __bf16 bf16_t;
typedef bf16_t bf16x8 __attribute__((ext_vector_type(8)));
typedef float f32x4 __attribute__((ext_vector_type(4)));
typedef float f32x16 __attribute__((ext_vector_type(16)));

#define MFMA16(a,b,c) __builtin_amdgcn_mfma_f32_16x16x32_bf16(a,b,c,0,0,0)
#define MFMA32(a,b,c) __builtin_amdgcn_mfma_f32_32x32x16_bf16(a,b,c,0,0,0)

static constexpr int SEQ = 2048, BATCH = 2, EMBED = 1024, NH = 16, QKD = 64;
static constexpr int M_TOT = BATCH * SEQ;   // 4096
static constexpr int N_TOT = 2 * NH * QKD;  // 2048 (Q cols 0..1023, K cols 1024..2047)
static constexpr float C1 = 0.125f * 1.44269504088896340736f; // SCALE*log2(e)

#define GLL16(g, l) __builtin_amdgcn_global_load_lds(                       \
    (const __attribute__((address_space(1))) void*)(g),                     \
    (__attribute__((address_space(3))) void*)(l), 16, 0, 0)

// ---- f32 -> bf16 bulk convert (vectorized, memory-bound) ----
__global__ __launch_bounds__(256) void cvt_kernel(
    const float* __restrict__ in, bf16_t* __restrict__ out, int n8)
{
    int i = blockIdx.x * 256 + threadIdx.x;
    const int stride = gridDim.x * 256;
    for (; i < n8; i += stride) {
        const f32x4* p = (const f32x4*)(in + (size_t)i * 8);
        f32x4 a = p[0], b = p[1];
        bf16x8 r;
        r[0]=(bf16_t)a[0]; r[1]=(bf16_t)a[1]; r[2]=(bf16_t)a[2]; r[3]=(bf16_t)a[3];
        r[4]=(bf16_t)b[0]; r[5]=(bf16_t)b[1]; r[6]=(bf16_t)b[2]; r[7]=(bf16_t)b[3];
        *(bf16x8*)(out + (size_t)i * 8) = r;
    }
}

// ---- Phase 1: C[m][n] = sum_d A[m][d]*B[n][d] + bias, bf16 out ----
// A = hsb (4096x1024 bf16), B = projb (2048x1024 bf16). 128x128 tile, BK=32.
// LDS tiles [128][32] bf16, granule-swizzle: byte16-slot ^= (row>>1)&3.
__global__ __launch_bounds__(256) void proj_kernel(
    const bf16_t* __restrict__ A, const bf16_t* __restrict__ B,
    const float* __restrict__ qb, const float* __restrict__ kb,
    bf16_t* __restrict__ C)
{
    __shared__ __align__(16) char sA[8192];
    __shared__ __align__(16) char sB[8192];
    const int t = threadIdx.x;
    const int lane = t & 63, wv = t >> 6;
    const int am0 = blockIdx.y * 128, bn0 = blockIdx.x * 128;
    const int wr = wv >> 1, wc = wv & 1;
    const int l15 = lane & 15, g = lane >> 4;

    // staging: per issue-half (64 rows) thread covers row 16*wv+(lane>>2), chunk lane&3
    const int st_r = 16 * wv + (lane >> 2);
    const int st_e = 8 * ((lane & 3) ^ ((lane >> 3) & 3));  // swizzled elem in 32-col
    const bf16_t* ga = A + (size_t)(am0 + st_r) * EMBED + st_e;
    const bf16_t* gb = B + (size_t)(bn0 + st_r) * EMBED + st_e;
    char* la = sA + wv * 1024;
    char* lb = sB + wv * 1024;

    f32x4 acc[4][4] = {};
    for (int kk = 0; kk < EMBED; kk += 32) {
        __syncthreads();
        GLL16(ga + kk,                   la);
        GLL16(ga + kk + 64 * EMBED,      la + 4096);
        GLL16(gb + kk,                   lb);
        GLL16(gb + kk + 64 * EMBED,      lb + 4096);
        __syncthreads();

        bf16x8 af[4], bfv[4];
        const int sw = 16 * (g ^ ((l15 >> 1) & 3));
#pragma unroll
        for (int mt = 0; mt < 4; ++mt) {
            int row = wr * 64 + mt * 16 + l15;
            af[mt] = *(const bf16x8*)(sA + row * 64 + sw);
        }
#pragma unroll
        for (int nt = 0; nt < 4; ++nt) {
            int row = wc * 64 + nt * 16 + l15;
            bfv[nt] = *(const bf16x8*)(sB + row * 64 + sw);
        }
#pragma unroll
        for (int mt = 0; mt < 4; ++mt)
#pragma unroll
            for (int nt = 0; nt < 4; ++nt)
                acc[mt][nt] = MFMA16(af[mt], bfv[nt], acc[mt][nt]);
    }

    // epilogue: C/D 16x16 layout col=lane&15, row=(lane>>4)*4+j
#pragma unroll
    for (int nt = 0; nt < 4; ++nt) {
        int col = bn0 + wc * 64 + nt * 16 + l15;
        float bias, scale;
        if (col < NH * QKD) { bias = qb[col & 63]; scale = C1; }   // Q: fold SCALE*log2e
        else                { bias = kb[col & 63]; scale = 1.0f; }
#pragma unroll
        for (int mt = 0; mt < 4; ++mt)
#pragma unroll
            for (int j = 0; j < 4; ++j) {
                int row = am0 + wr * 64 + mt * 16 + g * 4 + j;
                C[(size_t)row * N_TOT + col] = (bf16_t)((acc[mt][nt][j] + bias) * scale);
            }
    }
}

// ---- Phase 2: per (b,h): rowwise sum of exp2(Q K^T), partial sum of log2 ----
// Block: 4 waves x 32 Q-rows = 128 rows. K staged in LDS 256-row chunks,
// [256][64] bf16 with byte ^= (row&7)<<4 swizzle (128B rows -> 32-way fix).
__global__ __launch_bounds__(256) void lse_kernel(
    const bf16_t* __restrict__ qk, float* __restrict__ partials)
{
    __shared__ __align__(16) char sK[32768];
    const int t = threadIdx.x, lane = t & 63, wv = t >> 6;
    const int pair = blockIdx.y, b = pair >> 4, h = pair & 15;
    const int qr0 = blockIdx.x * 128;
    const int l31 = lane & 31, g5 = lane >> 5;
    const size_t base = (size_t)b * SEQ;

    // Q fragments (A operand, 32x32x16): row=l31, k=(kf*16 + g5*8)
    bf16x8 qf[4];
    const bf16_t* qptr = qk + (base + qr0 + wv * 32 + l31) * N_TOT + h * QKD + g5 * 8;
#pragma unroll
    for (int kf = 0; kf < 4; ++kf) qf[kf] = *(const bf16x8*)(qptr + kf * 16);

    // staging: per 32-row issue: row = wv*8 + (lane>>3), granule c = lane&7
    const int st_r = wv * 8 + (lane >> 3);
    const int st_e = 8 * ((lane & 7) ^ ((lane >> 3) & 7));
    const bf16_t* kptr = qk + (base + st_r) * N_TOT + NH * QKD + h * QKD + st_e;
    char* ldst = sK + wv * 1024;

    float sume[16];
#pragma unroll
    for (int j = 0; j < 16; ++j) sume[j] = 0.f;

    for (int kc = 0; kc < SEQ; kc += 256) {
        __syncthreads();
#pragma unroll
        for (int is = 0; is < 8; ++is)
            GLL16(kptr + (size_t)(kc + 32 * is) * N_TOT, ldst + is * 4096);
        __syncthreads();

#pragma unroll
        for (int ct = 0; ct < 8; ++ct) {
            f32x16 s = {};
            const int row = ct * 32 + l31;
#pragma unroll
            for (int kf = 0; kf < 4; ++kf) {
                bf16x8 kv = *(const bf16x8*)(sK + row * 128 + 16 * ((2 * kf + g5) ^ (lane & 7)));
                s = MFMA32(qf[kf], kv, s);
            }
#pragma unroll
            for (int j = 0; j < 16; ++j)
                sume[j] += __builtin_amdgcn_exp2f(s[j]);
        }
    }

    // reduce across 32 score-cols (lane&31), then log2 per row, sum rows.
#pragma unroll
    for (int j = 0; j < 16; ++j) {
#pragma unroll
        for (int m = 1; m < 32; m <<= 1)
            sume[j] += __shfl_xor(sume[j], m);
    }
    float tt = 0.f;
#pragma unroll
    for (int j = 0; j < 16; ++j) tt += __builtin_amdgcn_logf(sume[j]);
    tt += __shfl_xor(tt, 32);   // add other 16-row half

    __shared__ float wsum[4];
    if (lane == 0) wsum[wv] = tt;
    __syncthreads();
    if (t == 0)
        partials[blockIdx.y * gridDim.x + blockIdx.x] = wsum[0] + wsum[1] + wsum[2] + wsum[3];
}

__global__ __launch_bounds__(256) void final_kernel(
    const float* __restrict__ partials, int n, float* __restrict__ out)
{
    float s = 0.f;
    for (int i = threadIdx.x; i < n; i += 256) s += partials[i];
#pragma unroll
    for (int m = 1; m < 64; m <<= 1) s += __shfl_xor(s, m);
    __shared__ float ws[4];
    const int wave = threadIdx.x >> 6, lane = threadIdx.x & 63;
    if (lane == 0) ws[wave] = s;
    __syncthreads();
    if (threadIdx.x == 0)
        out[0] = -8.0f * 0.69314718055994530942f * (ws[0] + ws[1] + ws[2] + ws[3]);
}

extern "C" void kernel_launch(void* const* d_in, const int* in_sizes, int n_in,
                              void* d_out, int out_size, void* d_ws, size_t ws_size,
                              hipStream_t stream)
{
    const float* hs = (const float*)d_in[0];
    const float* qp = (const float*)d_in[1];
    const float* kp = (const float*)d_in[2];
    const float* qb = (const float*)d_in[3];
    const float* kb = (const float*)d_in[4];

    // ws layout: hsb (8MB) | projb (4MB) | qk (16MB) | partials
    bf16_t* hsb   = (bf16_t*)d_ws;
    bf16_t* projb = hsb + (size_t)M_TOT * EMBED;
    bf16_t* qkb   = projb + (size_t)N_TOT * EMBED;
    float*  partials = (float*)(qkb + (size_t)M_TOT * N_TOT);
    float*  out = (float*)d_out;

    cvt_kernel<<<2048, 256, 0, stream>>>(hs, hsb, M_TOT * EMBED / 8);
    cvt_kernel<<<512, 256, 0, stream>>>(qp, projb, NH * QKD * EMBED / 8);
    cvt_kernel<<<512, 256, 0, stream>>>(kp, projb + (size_t)NH * QKD * EMBED,
                                        NH * QKD * EMBED / 8);
    proj_kernel<<<dim3(N_TOT / 128, M_TOT / 128), 256, 0, stream>>>(
        hsb, projb, qb, kb, qkb);
    lse_kernel<<<dim3(SEQ / 128, BATCH * NH), 256, 0, stream>>>(qkb, partials);
    final_kernel<<<1, 256, 0, stream>>>(partials, (BATCH * NH) * (SEQ / 128), out);
}

// Round 3
// 58.713 us; speedup vs baseline: 6.8970x; 1.2167x over previous
//
#include <hip/hip_runtime.h>
#include <hip/hip_bf16.h>
#include <stdint.h>

// EnergyAttention: out = -sum(logsumexp(SCALE * (Q K^T), axis=-1)) / SCALE
// Q = hs @ qp^T + qb (pre-scaled by SCALE*log2e), K = hs @ kp^T + kb, bf16.

typedef __bf16 bf16_t;
typedef bf16_t bf16x8 __attribute__((ext_vector_type(8)));
typedef float f32x4 __attribute__((ext_vector_type(4)));
typedef float f32x16 __attribute__((ext_vector_type(16)));

#define MFMA16(a,b,c) __builtin_amdgcn_mfma_f32_16x16x32_bf16(a,b,c,0,0,0)
#define MFMA32(a,b,c) __builtin_amdgcn_mfma_f32_32x32x16_bf16(a,b,c,0,0,0)
#define GLL16(g, l) __builtin_amdgcn_global_load_lds(                       \
    (const __attribute__((address_space(1))) void*)(g),                     \
    (__attribute__((address_space(3))) void*)(l), 16, 0, 0)

static constexpr int SEQ = 2048, BATCH = 2, EMBED = 1024, NH = 16, QKD = 64;
static constexpr int M_TOT = BATCH * SEQ;   // 4096
static constexpr int N_TOT = 2 * NH * QKD;  // 2048 (Q cols 0..1023, K cols 1024..2047)
static constexpr float C1 = 0.125f * 1.44269504088896340736f; // SCALE*log2(e)

// ---- single-launch f32 -> bf16 convert of hs, qp, kp ----
__global__ __launch_bounds__(256) void cvt_kernel(
    const float* __restrict__ hs, const float* __restrict__ qp,
    const float* __restrict__ kp, bf16_t* __restrict__ hsb,
    bf16_t* __restrict__ projb)
{
    int i = blockIdx.x * 256 + threadIdx.x;   // vec8 index, 786432 total
    const float* src; bf16_t* dst;
    if (i < 524288) { src = hs + (size_t)i * 8; dst = hsb + (size_t)i * 8; }
    else {
        int j = i - 524288;
        dst = projb + (size_t)j * 8;
        src = (j < 131072) ? qp + (size_t)j * 8 : kp + (size_t)(j - 131072) * 8;
    }
    f32x4 a = ((const f32x4*)src)[0], b = ((const f32x4*)src)[1];
    bf16x8 r;
    r[0]=(bf16_t)a[0]; r[1]=(bf16_t)a[1]; r[2]=(bf16_t)a[2]; r[3]=(bf16_t)a[3];
    r[4]=(bf16_t)b[0]; r[5]=(bf16_t)b[1]; r[6]=(bf16_t)b[2]; r[7]=(bf16_t)b[3];
    *(bf16x8*)dst = r;
}

// ---- Phase 1: C[m][n] = sum_d A[m][d]*B[n][d] + bias, bf16 out ----
// 128x128 tile, BK=64, double-buffered LDS (2x16KB per operand), 1 barrier/K-step.
// LDS rows 128B; granule (16B) XOR-swizzled by row&7 via pre-swizzled global src.
__global__ __launch_bounds__(256) void proj_kernel(
    const bf16_t* __restrict__ A, const bf16_t* __restrict__ B,
    const float* __restrict__ qb, const float* __restrict__ kb,
    bf16_t* __restrict__ C)
{
    __shared__ __align__(16) char sA[2][16384];
    __shared__ __align__(16) char sB[2][16384];
    const int t = threadIdx.x, lane = t & 63, wv = t >> 6;
    const int bid = blockIdx.x;
    const int xcd = bid & 7, idx = bid >> 3;
    const int am0 = (xcd * 4 + (idx >> 4)) * 128;   // M-strip per XCD
    const int bn0 = (idx & 15) * 128;
    const int wr = wv >> 1, wc = wv & 1;
    const int l15 = lane & 15, g = lane >> 4;

    // staging: thread covers LDS (row = is*32 + wv*8 + lane>>3, granule = lane&7);
    // source granule pre-swizzled: ^ (row&7) = ^ ((lane>>3)&7)
    const int srow = wv * 8 + (lane >> 3);
    const int sgr  = (lane & 7) ^ ((lane >> 3) & 7);
    const bf16_t* ga = A + (size_t)(am0 + srow) * EMBED + sgr * 8;
    const bf16_t* gb = B + (size_t)(bn0 + srow) * EMBED + sgr * 8;
    const int lbase = wv * 1024;

    f32x4 acc[4][4] = {};

#pragma unroll
    for (int is = 0; is < 4; ++is) {
        GLL16(ga + (size_t)is * 32 * EMBED, &sA[0][lbase + is * 4096]);
        GLL16(gb + (size_t)is * 32 * EMBED, &sB[0][lbase + is * 4096]);
    }
    __syncthreads();

    int cur = 0;
    for (int kk = 0; kk < EMBED; kk += 64) {
        if (kk + 64 < EMBED) {
#pragma unroll
            for (int is = 0; is < 4; ++is) {
                GLL16(ga + kk + 64 + (size_t)is * 32 * EMBED, &sA[cur ^ 1][lbase + is * 4096]);
                GLL16(gb + kk + 64 + (size_t)is * 32 * EMBED, &sB[cur ^ 1][lbase + is * 4096]);
            }
        }
#pragma unroll
        for (int s = 0; s < 2; ++s) {
            bf16x8 af[4], bfv[4];
#pragma unroll
            for (int mt = 0; mt < 4; ++mt) {
                int row = wr * 64 + mt * 16 + l15;
                af[mt] = *(const bf16x8*)&sA[cur][row * 128 + 16 * (((s << 2) | g) ^ (row & 7))];
            }
#pragma unroll
            for (int nt = 0; nt < 4; ++nt) {
                int row = wc * 64 + nt * 16 + l15;
                bfv[nt] = *(const bf16x8*)&sB[cur][row * 128 + 16 * (((s << 2) | g) ^ (row & 7))];
            }
#pragma unroll
            for (int mt = 0; mt < 4; ++mt)
#pragma unroll
                for (int nt = 0; nt < 4; ++nt)
                    acc[mt][nt] = MFMA16(af[mt], bfv[nt], acc[mt][nt]);
        }
        __syncthreads();   // drains vmcnt (stage done) + lgkmcnt (reads done)
        cur ^= 1;
    }

    // epilogue: C/D 16x16 layout col=lane&15, row=(lane>>4)*4+j
#pragma unroll
    for (int nt = 0; nt < 4; ++nt) {
        int col = bn0 + wc * 64 + nt * 16 + l15;
        float bias, scale;
        if (col < NH * QKD) { bias = qb[col & 63]; scale = C1; }   // Q: fold SCALE*log2e
        else                { bias = kb[col & 63]; scale = 1.0f; }
#pragma unroll
        for (int mt = 0; mt < 4; ++mt)
#pragma unroll
            for (int j = 0; j < 4; ++j) {
                int row = am0 + wr * 64 + mt * 16 + g * 4 + j;
                C[(size_t)row * N_TOT + col] = (bf16_t)((acc[mt][nt][j] + bias) * scale);
            }
    }
}

// ---- Phase 2: per (b,h): rowwise sum of exp2(Q K^T), partial sum of log2 ----
// Block = 4 waves, all on the SAME 128 Q-rows; wave wv covers K rows
// [wv*512, wv*512+512). Operand-swapped MFMA: s = mfma(K, Q) puts the K-row
// (reduction) axis on registers -> per-lane in-register sum of exp2. No LDS
// staging (K is L2-resident), no barriers in the main loop.
__global__ __launch_bounds__(256) void lse_kernel(
    const bf16_t* __restrict__ qk, float* __restrict__ partials)
{
    __shared__ float rows_s[4][128];
    __shared__ float ws[4];
    const int t = threadIdx.x, lane = t & 63, wv = t >> 6;
    const int bid = blockIdx.x;
    const int xcd = bid & 7, idx = bid >> 3;
    const int pair = xcd * 4 + (idx >> 4);    // all 16 tiles of a pair on one XCD
    const int tile = idx & 15;
    const int b = pair >> 4, h = pair & 15;
    const int qr0 = tile * 128;
    const int l31 = lane & 31, g5 = lane >> 5;
    const size_t base = (size_t)b * SEQ;

    // Q fragments (B-operand): lane holds Q-row qr0+mt*32+l31, k = kf*16+g5*8
    bf16x8 qf[4][4];
#pragma unroll
    for (int mt = 0; mt < 4; ++mt) {
        const bf16_t* qp_ = qk + (base + qr0 + mt * 32 + l31) * N_TOT + h * QKD + g5 * 8;
#pragma unroll
        for (int kf = 0; kf < 4; ++kf)
            qf[mt][kf] = *(const bf16x8*)(qp_ + kf * 16);
    }

    // K fragment base (A-operand): lane holds K-row (wv*512 + ct*32 + l31)
    const bf16_t* kb_ = qk + (base + wv * 512 + l31) * N_TOT + NH * QKD + h * QKD + g5 * 8;

    float sume[4] = {0.f, 0.f, 0.f, 0.f};

    bf16x8 kv[4];
#pragma unroll
    for (int kf = 0; kf < 4; ++kf) kv[kf] = *(const bf16x8*)(kb_ + kf * 16);

    for (int ct = 0; ct < 16; ++ct) {
        // prefetch next K-frag set (clamped on last iter)
        bf16x8 kn[4];
        const bf16_t* kn_p = kb_ + (size_t)((ct < 15 ? ct + 1 : 15) * 32) * N_TOT;
#pragma unroll
        for (int kf = 0; kf < 4; ++kf) kn[kf] = *(const bf16x8*)(kn_p + kf * 16);

        // 16 back-to-back MFMA32 (4 independent accumulators), then 64 exp2
        f32x16 sacc[4];
#pragma unroll
        for (int mt = 0; mt < 4; ++mt) {
            f32x16 z = {};
            sacc[mt] = z;
#pragma unroll
            for (int kf = 0; kf < 4; ++kf)
                sacc[mt] = MFMA32(kv[kf], qf[mt][kf], sacc[mt]);
        }
#pragma unroll
        for (int mt = 0; mt < 4; ++mt) {
            float e = 0.f;
#pragma unroll
            for (int j = 0; j < 16; ++j)
                e += __builtin_amdgcn_exp2f(sacc[mt][j]);
            sume[mt] += e;
        }
#pragma unroll
        for (int kf = 0; kf < 4; ++kf) kv[kf] = kn[kf];
    }

    // lane + its g5-partner cover all 32 K-rows of each ct for the same Q-row
#pragma unroll
    for (int mt = 0; mt < 4; ++mt) {
        float v = sume[mt] + __shfl_xor(sume[mt], 32);
        if (g5 == 0) rows_s[wv][mt * 32 + l31] = v;
    }
    __syncthreads();

    float lg = 0.f;
    if (t < 128) {
        float tot = rows_s[0][t] + rows_s[1][t] + rows_s[2][t] + rows_s[3][t];
        lg = __builtin_amdgcn_logf(tot);   // v_log_f32 = log2
    }
#pragma unroll
    for (int m = 1; m < 64; m <<= 1) lg += __shfl_xor(lg, m);
    if (lane == 0) ws[wv] = lg;
    __syncthreads();
    if (t == 0)
        partials[bid] = ws[0] + ws[1] + ws[2] + ws[3];
}

__global__ __launch_bounds__(256) void final_kernel(
    const float* __restrict__ partials, int n, float* __restrict__ out)
{
    float s = 0.f;
    for (int i = threadIdx.x; i < n; i += 256) s += partials[i];
#pragma unroll
    for (int m = 1; m < 64; m <<= 1) s += __shfl_xor(s, m);
    __shared__ float wsf[4];
    const int wave = threadIdx.x >> 6, lane = threadIdx.x & 63;
    if (lane == 0) wsf[wave] = s;
    __syncthreads();
    if (threadIdx.x == 0)
        out[0] = -8.0f * 0.69314718055994530942f * (wsf[0] + wsf[1] + wsf[2] + wsf[3]);
}

extern "C" void kernel_launch(void* const* d_in, const int* in_sizes, int n_in,
                              void* d_out, int out_size, void* d_ws, size_t ws_size,
                              hipStream_t stream)
{
    const float* hs = (const float*)d_in[0];
    const float* qp = (const float*)d_in[1];
    const float* kp = (const float*)d_in[2];
    const float* qb = (const float*)d_in[3];
    const float* kb = (const float*)d_in[4];

    // ws layout: hsb (8MB) | projb (4MB) | qk (16MB) | partials (2KB)
    bf16_t* hsb   = (bf16_t*)d_ws;
    bf16_t* projb = hsb + (size_t)M_TOT * EMBED;
    bf16_t* qkb   = projb + (size_t)N_TOT * EMBED;
    float*  partials = (float*)(qkb + (size_t)M_TOT * N_TOT);
    float*  out = (float*)d_out;

    cvt_kernel<<<3072, 256, 0, stream>>>(hs, qp, kp, hsb, projb);
    proj_kernel<<<512, 256, 0, stream>>>(hsb, projb, qb, kb, qkb);
    lse_kernel<<<512, 256, 0, stream>>>(qkb, partials);
    final_kernel<<<1, 256, 0, stream>>>(partials, 512, out);
}